// Round 4
// baseline (319.020 us; speedup 1.0000x reference)
//
#include <hip/hip_runtime.h>

#define MAXT   10000
#define BATCH  4096
#define NXB    4
#define NYB    80
#define NBLK   (NXB * NYB)      // 320 blocks
#define TCHUNK 16
#define CHTOT  (MAXT / TCHUNK)  // 625 chunks
#define SEGT   1536             // t-steps per gate-prefix segment (256*6)
#define EPT    6
#define CHPS   (SEGT / TCHUNK)  // 96 chunks per segment
#define SEGF   40               // finalize prefix elems/thread (256*40 = 10240)

#define LOG_GAMMA_C  1.9802627296e-2f   // log(1.02)
#define ALPHA_C     -1.0050335854e-5f   // log(0.99)/1000
#define INIT_LOGW_C -1.3943265329f      // log(0.248)
#define INIT_LOGP_C -6.9077552790f      // log(0.001)
#define EPS_C        1e-12f
// gate = odds - EPS stored; odds <= 9.3e-13 (logit <= -27.7 < -log(1e-12)) => no fire possible
#define CUT_GATE    (9.3e-13f - 1e-12f)

// ---- wave-inclusive scan over 64 lanes (shuffles, no LDS) ----------------
__device__ __forceinline__ float wave_inscan(float v, int lane) {
    #pragma unroll
    for (int off = 1; off < 64; off <<= 1) {
        float x = __shfl_up(v, off, 64);
        if (lane >= off) v += x;
    }
    return v;
}

// ---- block exclusive scan (256 thr) + total; 2 barriers ------------------
// -inf-safe: exclusive taken from neighbor's inclusive (shfl_up), never incl-v.
__device__ __forceinline__ float block_exscan(float v, int tid, float* shw,
                                              float* tot) {
    const int lane = tid & 63, wave = tid >> 6;
    float win = wave_inscan(v, lane);
    float wex = __shfl_up(win, 1, 64);
    if (lane == 0) wex = 0.0f;
    if (lane == 63) shw[wave] = win;
    __syncthreads();
    float pre = 0.0f, t_ = 0.0f;
    #pragma unroll
    for (int w = 0; w < 4; ++w) {
        float wt = shw[w];
        if (w < wave) pre += wt;
        t_ += wt;
    }
    __syncthreads();            // shw reusable by next call
    *tot = t_;
    return pre + wex;
}

__device__ __forceinline__ void gate_test(float4 a, float4 c, unsigned t, float k,
                                          unsigned& f0, unsigned& f1,
                                          unsigned& f2, unsigned& f3) {
    const float E = EPS_C;
    // fire iff log(u2+E)/log(u1+E) + E < exp(logit)  <=>  L2 > gate*L1 (L1<0)
    if (__logf(c.x + E) > k * __logf(a.x + E)) f0 = min(f0, t);
    if (__logf(c.y + E) > k * __logf(a.y + E)) f1 = min(f1, t);
    if (__logf(c.z + E) > k * __logf(a.z + E)) f2 = min(f2, t);
    if (__logf(c.w + E) > k * __logf(a.w + E)) f3 = min(f3, t);
}

// ===== single fused kernel: gate prefix + first-fire scan + finalize ======
__global__ __launch_bounds__(256, 1) void fused_kernel(
    const float* __restrict__ acts,
    const float* __restrict__ u1, const float* __restrict__ u2,
    unsigned* __restrict__ ffrow,   // [BATCH], pre-memset 0xFF
    unsigned* __restrict__ cnt,     // pre-memset 0
    float* __restrict__ out)
{
    __shared__ float    shw[4];
    __shared__ float    s_gate[SEGT];
    __shared__ unsigned s_ticket;
    __shared__ double   sdw[4];

    const int tid = threadIdx.x;
    const int y   = blockIdx.y;
    const int b4  = (blockIdx.x * 256 + tid) * 4;
    const float E = EPS_C;

    // ---- speculative prefetch of this block's first owned chunk ----------
    // (t in [16y, 16y+16), always < MAXT; held in regs across the prefix)
    const int tpre = TCHUNK * y;
    float4 pa[TCHUNK], pc[TCHUNK];
    #pragma unroll
    for (int j = 0; j < TCHUNK; ++j) {
        pa[j] = *(const float4*)(u1 + (size_t)(tpre + j) * BATCH + b4);
        pc[j] = *(const float4*)(u2 + (size_t)(tpre + j) * BATCH + b4);
    }

    unsigned f0 = ~0u, f1 = ~0u, f2 = ~0u, f3 = ~0u;
    float carry_w = INIT_LOGW_C, carry_p = INIT_LOGP_C;

    for (int seg = 0; seg * SEGT < MAXT; ++seg) {
        const int seg_base = seg * SEGT;

        // ---- gate prefix for t in [seg_base, seg_base + SEGT) ----
        float fv[EPT], dv[EPT];
        float lsum = 0.0f;
        #pragma unroll
        for (int i = 0; i < EPT; ++i) {
            int t = seg_base + tid * EPT + i;
            if (t < MAXT) {
                float f = expf(acts[t]);
                fv[i] = f;
                dv[i] = LOG_GAMMA_C + logf(1.0f - f);
            } else { fv[i] = 0.0f; dv[i] = 0.0f; }
            lsum += dv[i];
        }
        float dtot;
        float dex = block_exscan(lsum, tid, shw, &dtot);

        float run = carry_w + dex;          // logw BEFORE step t
        float cv[EPT], csum = 0.0f;
        #pragma unroll
        for (int i = 0; i < EPT; ++i) {
            cv[i] = ALPHA_C * fv[i] * expf(run);   // uses OLD logw (ref semantics)
            run += dv[i];
            csum += cv[i];
        }
        float ctot;
        float cex = block_exscan(csum, tid, shw, &ctot);

        float logp = carry_p + cex;         // logp BEFORE step t
        #pragma unroll
        for (int i = 0; i < EPT; ++i) {
            int idx = tid * EPT + i;
            int t   = seg_base + idx;
            float el   = (t < MAXT) ? expf(logp) : 0.0f;   // pad => dead
            float odds = el / (1.0f - el);                 // = exp(logit)
            s_gate[idx] = odds - E;
            logp += cv[i];
        }
        __syncthreads();

        // ---- scan this block's owned chunks inside the segment ----
        const int c0 = seg * CHPS, c1 = min(c0 + CHPS, CHTOT);
        for (int cg = y; cg < CHTOT; cg += NYB) {
            if (cg < c0) continue;
            if (cg >= c1) break;
            const int tstart = cg * TCHUNK;
            const int idx0   = tstart - seg_base;
            // odds monotone non-increasing in t: dead at chunk start => dead forever
            if (s_gate[idx0] <= CUT_GATE) break;
            if (cg == y) {
                // prefetched in regs
                #pragma unroll
                for (int g = 0; g < TCHUNK; ++g)
                    gate_test(pa[g], pc[g], (unsigned)(tstart + g),
                              s_gate[idx0 + g], f0, f1, f2, f3);
            } else {
                #pragma unroll
                for (int q = 0; q < TCHUNK / 4; ++q) {
                    float4 a[4], c[4];
                    float gv[4];
                    #pragma unroll
                    for (int j = 0; j < 4; ++j) {
                        const int t = tstart + q * 4 + j;
                        a[j]  = *(const float4*)(u1 + (size_t)t * BATCH + b4);
                        c[j]  = *(const float4*)(u2 + (size_t)t * BATCH + b4);
                        gv[j] = s_gate[idx0 + q * 4 + j];
                    }
                    #pragma unroll
                    for (int j = 0; j < 4; ++j)
                        gate_test(a[j], c[j], (unsigned)(tstart + q * 4 + j),
                                  gv[j], f0, f1, f2, f3);
                }
            }
        }

        if (s_gate[SEGT - 1] <= CUT_GATE) break;   // uniform: dead beyond segment
        carry_w += dtot;
        carry_p += ctot;
        __syncthreads();                            // s_gate overwrite next segment
    }

    // ---- record fires (device-scope atomics; rare => ~no contention) ----
    if (f0 != ~0u) atomicMin(ffrow + b4 + 0, f0);
    if (f1 != ~0u) atomicMin(ffrow + b4 + 1, f1);
    if (f2 != ~0u) atomicMin(ffrow + b4 + 2, f2);
    if (f3 != ~0u) atomicMin(ffrow + b4 + 3, f3);

    // ---- last-block-done ticket ----
    __syncthreads();                 // drain this block's vmem (incl. atomics)
    if (tid == 0) {
        __threadfence();             // release prior atomics before ticket
        s_ticket = atomicAdd(cnt, 1u);
    }
    __syncthreads();
    if (s_ticket != NBLK - 1) return;

    // ===================== last block: finalize ===========================
    __threadfence();                 // acquire
    __shared__ float rp[MAXT + 1];   // exclusive prefix of r_t; [MAXT] = total

    const int t0 = tid * SEGF;
    float dvf[SEGF];
    float dsum = 0.0f;
    #pragma unroll 8
    for (int i = 0; i < SEGF; ++i) {
        int t = t0 + i;
        if (t < MAXT) {
            float f = expf(acts[t]);
            dvf[i] = LOG_GAMMA_C + logf(1.0f - f);
        } else dvf[i] = 0.0f;
        dsum += dvf[i];
    }
    float dt_;
    float dex = block_exscan(dsum, tid, shw, &dt_);
    float run = INIT_LOGW_C + dex;   // logw BEFORE step t

    float rvf[SEGF];
    float rsum = 0.0f;
    #pragma unroll 8
    for (int i = 0; i < SEGF; ++i) {
        run += dvf[i];                       // logw AFTER step t
        rvf[i] = ((t0 + i) < MAXT) ? expf(run * 1e-3f) : 0.0f;
        rsum += rvf[i];
    }
    float rtot;
    float rex = block_exscan(rsum, tid, shw, &rtot);
    float rr = rex;
    #pragma unroll 8
    for (int i = 0; i < SEGF; ++i) {
        int t = t0 + i;
        if (t < MAXT) rp[t] = rr;
        rr += rvf[i];
    }
    if (tid == 0) rp[MAXT] = rtot;           // never-fired -> full sum
    __syncthreads();

    double s = 0.0;
    for (int b = tid; b < BATCH; b += 256) {
        // atomic RMW read: coherent across XCDs; also clamps never-fired to MAXT
        unsigned ff = atomicMin(ffrow + b, (unsigned)MAXT);
        s += (double)rp[min(ff, (unsigned)MAXT)];
    }
    const int lane = tid & 63, wave = tid >> 6;
    #pragma unroll
    for (int off = 32; off > 0; off >>= 1) s += __shfl_down(s, off, 64);
    if (lane == 0) sdw[wave] = s;
    __syncthreads();
    if (tid == 0)
        out[0] = (float)((sdw[0] + sdw[1] + sdw[2] + sdw[3]) / (double)BATCH);
}

extern "C" void kernel_launch(void* const* d_in, const int* in_sizes, int n_in,
                              void* d_out, int out_size, void* d_ws, size_t ws_size,
                              hipStream_t stream) {
    const float* acts = (const float*)d_in[0];
    const float* u1   = (const float*)d_in[1];
    const float* u2   = (const float*)d_in[2];
    float* out = (float*)d_out;

    unsigned* cnt   = (unsigned*)d_ws;      // 1 uint (ticket counter)
    unsigned* ffrow = cnt + 64;             // [BATCH] first-fire, 256B-aligned

    hipMemsetAsync(cnt, 0x00, sizeof(unsigned), stream);
    hipMemsetAsync(ffrow, 0xFF, BATCH * sizeof(unsigned), stream);

    dim3 grid(NXB, NYB);                    // 320 blocks
    fused_kernel<<<grid, 256, 0, stream>>>(acts, u1, u2, ffrow, cnt, out);
}